// Round 6
// baseline (275.692 us; speedup 1.0000x reference)
//
#include <hip/hip_runtime.h>
#include <hip/hip_bf16.h>

// Problem constants
#define D       512       // embedding dim (= C)
#define K       2048      // codebook size
#define HW      1024      // 32*32
#define N_TOK   16384     // 16*HW
#define NUMEL   8388608   // 16*512*32*32

typedef __attribute__((ext_vector_type(8))) short  short8;   // 8 bf16 = 4 VGPRs
typedef __attribute__((ext_vector_type(4))) float  floatx4;

// async global->LDS DMA, 16 B per lane; LDS dest is wave-uniform base + lane*16
#define GLD_LDS16(gptr, lptr) \
    __builtin_amdgcn_global_load_lds((const __attribute__((address_space(1))) void*)(gptr), \
                                     (__attribute__((address_space(3))) void*)(lptr), 16, 0, 0)

// ---- ws layout (bytes) ----
#define WS_ZB    0           // bf16 [16384][512]
#define WS_EB    16777216    // bf16 [2048][512]
#define WS_ESQ   18874368    // f32  [2048]
#define WS_MINB  18882560    // u32  [16384] packed (21-bit dist key | 11-bit idx); init in kp
#define WS_XSQ   18948096    // f32  [16384] per-token sum z^2       (memset 0)
#define WS_PARTS 19013632    // f32  [128]   loss partials           (memset 0)
#define WS_SCNT  19014144    // u32  [128]   per-strip completion    (memset 0)
#define WS_CNT2  19014656    // u32  [1]     global completion       (memset 0)
// memset region: WS_XSQ .. WS_CNT2+4 (contiguous, 66564 B)

// monotone fp32 -> sortable u32, and its inverse
__device__ __forceinline__ unsigned int fkey(float f) {
    unsigned int b = __float_as_uint(f);
    return b ^ ((unsigned int)((int)b >> 31) | 0x80000000u);
}
__device__ __forceinline__ float unfkey(unsigned int u) {
    unsigned int b = (u & 0x80000000u) ? (u ^ 0x80000000u) : ~u;
    return __uint_as_float(b);
}

// ---------------- Kernel P: fused prep ----------------
// blocks [0,2048): z NCHW fp32 -> zb bf16 (transpose+cast) + xsq accumulate + minb init
// blocks [2048,4096): emb row -> eb bf16 + e_sq
__global__ __launch_bounds__(256) void kp(const float* __restrict__ z,
                                          const float* __restrict__ emb,
                                          __hip_bfloat16* __restrict__ zb,
                                          __hip_bfloat16* __restrict__ eb,
                                          float* __restrict__ esq,
                                          float* __restrict__ xsq,
                                          unsigned int* __restrict__ minb) {
    int blk = blockIdx.x;
    int tid = threadIdx.x;
    if (blk < 2048) {
        if (tid < 8) minb[blk * 8 + tid] = 0xFFFFFFFFu;
        __shared__ float t[64][65];
        __shared__ float ps[4][64];
        int b  = blk >> 7;
        int dt = (blk >> 4) & 7;
        int nt = blk & 15;
        int d0 = dt * 64, n0 = nt * 64;
        const float* zp = z + ((size_t)b * D + d0) * HW + n0;
#pragma unroll
        for (int i = 0; i < 4; ++i) {
            int e = tid + 256 * i;     // r(64 ch) x c4(16)
            int r = e >> 4, c4 = e & 15;
            float4 v = *(const float4*)(zp + (size_t)r * HW + c4 * 4);
            t[r][c4 * 4 + 0] = v.x; t[r][c4 * 4 + 1] = v.y;
            t[r][c4 * 4 + 2] = v.z; t[r][c4 * 4 + 3] = v.w;
        }
        __syncthreads();
        {   // xsq partial: quad q covers 16 channels of one token column
            int col = tid & 63, q = tid >> 6;
            float p = 0.f;
#pragma unroll
            for (int j = 0; j < 16; ++j) { float v = t[q * 16 + j][col]; p += v * v; }
            ps[q][col] = p;
        }
        __syncthreads();
        if (tid < 64)
            atomicAdd(&xsq[b * HW + n0 + tid], ps[0][tid] + ps[1][tid] + ps[2][tid] + ps[3][tid]);
        __hip_bfloat16* op = zb + ((size_t)(b * HW + n0)) * D + d0;
#pragma unroll
        for (int i = 0; i < 4; ++i) {
            int e = tid + 256 * i;     // rn(64 tok) x cd4(16)
            int rn = e >> 4, cd4 = e & 15;
            __hip_bfloat16 q0 = __float2bfloat16(t[cd4 * 4 + 0][rn]);
            __hip_bfloat16 q1 = __float2bfloat16(t[cd4 * 4 + 1][rn]);
            __hip_bfloat16 q2 = __float2bfloat16(t[cd4 * 4 + 2][rn]);
            __hip_bfloat16 q3 = __float2bfloat16(t[cd4 * 4 + 3][rn]);
            ushort4 u;
            u.x = *(unsigned short*)&q0; u.y = *(unsigned short*)&q1;
            u.z = *(unsigned short*)&q2; u.w = *(unsigned short*)&q3;
            *(ushort4*)(op + (size_t)rn * D + cd4 * 4) = u;
        }
    } else {
        int k = blk - 2048;
        const float* ep = emb + (size_t)k * D;
        float s = 0.f;
        for (int d = tid; d < D; d += 256) {
            float v = ep[d];
            s += v * v;
            eb[(size_t)k * D + d] = __float2bfloat16(v);
        }
#pragma unroll
        for (int o = 32; o; o >>= 1) s += __shfl_down(s, o);
        __shared__ float ls[4];
        if ((tid & 63) == 0) ls[tid >> 6] = s;
        __syncthreads();
        if (tid == 0) esq[k] = ls[0] + ls[1] + ls[2] + ls[3];
    }
}

// ---------------- Kernel G2: R4 GEMM+argmin core, with output stage fused ----------------
// grid 2048 = 128 mtiles x 16 ktiles (mtile = blk>>4: the 16 blocks sharing an A
// strip dispatch simultaneously). LDS XOR col swizzle -> 0 bank conflicts (R4-proven).
// Last-finishing block of each mtile (scnt) re-reads merged keys and does loss
// partial + gather + NCHW write, reusing the dead As/Bs LDS for the transpose.
__global__ __launch_bounds__(256) void kg2(const __hip_bfloat16* __restrict__ zb,
                                           const __hip_bfloat16* __restrict__ eb,
                                           const float* __restrict__ esq,
                                           const float* __restrict__ emb,
                                           const float* __restrict__ xsq,
                                           unsigned int* __restrict__ minb,
                                           unsigned int* __restrict__ scnt,
                                           unsigned int* __restrict__ cnt2,
                                           float* __restrict__ parts,
                                           float* __restrict__ out) {
    __shared__ char smem[32768] __attribute__((aligned(16)));   // As | Bs, later mint | qt
    __hip_bfloat16* As = (__hip_bfloat16*)smem;                 // [128*64]
    __hip_bfloat16* Bs = (__hip_bfloat16*)(smem + 16384);       // [128*64]
    __shared__ float red[4];
    __shared__ int lastflag, finflag;

    int mtile = blockIdx.x >> 4;
    int ktile = blockIdx.x & 15;

    int tid  = threadIdx.x;
    int wv   = tid >> 6;
    int lane = tid & 63;
    int wm = wv >> 1, wn = wv & 1;   // 2x2 wave grid, each wave 64x64
    int lrow  = lane & 15;
    int lquad = lane >> 4;
    int rl = lane >> 3, c8 = lane & 7;      // staging: 8 rows x 8 uint4 per wave-call
    int csw = c8 ^ rl;                      // swizzled global col for this lane's slot
    int swz = lrow & 7;                     // read-side row swizzle

    floatx4 acc[4][4];
#pragma unroll
    for (int i = 0; i < 4; ++i)
#pragma unroll
        for (int j = 0; j < 4; ++j) acc[i][j] = (floatx4){0.f, 0.f, 0.f, 0.f};

    const uint4* Ag = (const uint4*)(zb + (size_t)mtile * 128 * D);  // [128][64] uint4
    const uint4* Bg = (const uint4*)(eb + (size_t)ktile * 128 * D);

    for (int d0 = 0; d0 < D; d0 += 64) {
        int c0 = d0 >> 3;   // uint4 col offset
#pragma unroll
        for (int ch = 0; ch < 4; ++ch) {
            int rbase = wv * 32 + ch * 8;    // wave-uniform
            GLD_LDS16(Ag + (size_t)(rbase + rl) * 64 + c0 + csw, &As[rbase * 64]);
            GLD_LDS16(Bg + (size_t)(rbase + rl) * 64 + c0 + csw, &Bs[rbase * 64]);
        }
        __syncthreads();
#pragma unroll
        for (int ks = 0; ks < 2; ++ks) {
            short8 af[4], bfr[4];
#pragma unroll
            for (int i = 0; i < 4; ++i) {
                int cL = (ks * 4 + lquad) ^ swz;          // swizzled uint4 col
                af[i]  = *(const short8*)&As[(wm * 64 + i * 16 + lrow) * 64 + (cL << 3)];
                bfr[i] = *(const short8*)&Bs[(wn * 64 + i * 16 + lrow) * 64 + (cL << 3)];
            }
#pragma unroll
            for (int i = 0; i < 4; ++i)
#pragma unroll
                for (int j = 0; j < 4; ++j)
                    acc[i][j] = __builtin_amdgcn_mfma_f32_16x16x32_bf16(af[i], bfr[j], acc[i][j], 0, 0, 0);
        }
        __syncthreads();
    }

    // ---- argmin epilogue: dist = esq[k] - 2*dot; u32 key = trunc-fkey | idx ----
    float es[4];
#pragma unroll
    for (int j = 0; j < 4; ++j) es[j] = esq[ktile * 128 + wn * 64 + j * 16 + lrow];

#pragma unroll
    for (int i = 0; i < 4; ++i) {
#pragma unroll
        for (int r = 0; r < 4; ++r) {
            int m_g = mtile * 128 + wm * 64 + i * 16 + lquad * 4 + r;  // C/D: row=quad*4+reg
            unsigned int best = 0xFFFFFFFFu;
#pragma unroll
            for (int j = 0; j < 4; ++j) {
                float dist = es[j] - 2.0f * acc[i][j][r];
                unsigned int kidx = (unsigned int)(ktile * 128 + wn * 64 + j * 16 + lrow);
                unsigned int p = (fkey(dist) & 0xFFFFF800u) | kidx;
                best = p < best ? p : best;
            }
#pragma unroll
            for (int o = 1; o < 16; o <<= 1) {
                unsigned int other = __shfl_xor(best, o);
                best = other < best ? other : best;
            }
            if (lrow == 0) atomicMin(&minb[m_g], best);
        }
    }

    // ---- strip completion: last of the 16 ktile-blocks does the output stage ----
    __syncthreads();                       // drains all waves' atomicMin (vmcnt before barrier)
    if (tid == 0) {
        __threadfence();
        lastflag = (atomicAdd(&scnt[mtile], 1u) == 15u);
    }
    __syncthreads();
    if (!lastflag) return;

    // As/Bs are dead now: alias for mint + qt
    unsigned int* mint = (unsigned int*)smem;            // [128]
    float (*qt)[65]    = (float(*)[65])(smem + 512);     // [64][65] = 16640 B

    if (tid < 128) mint[tid] = atomicMin(&minb[mtile * 128 + tid], 0xFFFFFFFFu);  // coherent read
    __syncthreads();

    // loss partial for the strip's 128 tokens: xsq + decoded min(esq - 2 dot)
    {
        float v = (tid < 128) ? (xsq[mtile * 128 + tid] + unfkey(mint[tid] & 0xFFFFF800u)) : 0.f;
#pragma unroll
        for (int o = 32; o; o >>= 1) v += __shfl_down(v, o);
        if ((tid & 63) == 0) red[tid >> 6] = v;
    }
    __syncthreads();
    if (tid == 0) {
        parts[mtile] = red[0] + red[1] + red[2] + red[3];
        __threadfence();
        finflag = (atomicAdd(cnt2, 1u) == 127u);
    }
    __syncthreads();
    if (finflag) {                         // last winner: final loss reduce (128 partials)
        float s = (tid < 128) ? atomicAdd(&parts[tid], 0.0f) : 0.f;   // device-coherent read
#pragma unroll
        for (int o = 32; o; o >>= 1) s += __shfl_down(s, o);
        if ((tid & 63) == 0) red[tid >> 6] = s;
        __syncthreads();
        if (tid == 0)
            out[NUMEL] = 1.25f * (red[0] + red[1] + red[2] + red[3]) / 8388608.0f;
    }

    // ---- gather + NCHW write for the strip's 128 tokens (tokens b, hw0..hw0+127) ----
    int b = mtile >> 3, hw0 = (mtile & 7) * 128;
    for (int th = 0; th < 2; ++th) {           // 2 halves of 64 tokens
        for (int ct = 0; ct < 8; ++ct) {       // 8 channel tiles of 64
            int c0 = ct * 64;
            __syncthreads();                   // protect qt reads of previous iteration
#pragma unroll
            for (int i = 0; i < 4; ++i) {
                int e = tid + 256 * i;         // tr(64) x c4(16): coalesced 256 B rows
                int tr = e >> 4, c4 = e & 15;
                float4 v = *(const float4*)(emb +
                    (size_t)(mint[th * 64 + tr] & 0x7FFu) * D + c0 + c4 * 4);
                qt[tr][c4 * 4 + 0] = v.x; qt[tr][c4 * 4 + 1] = v.y;
                qt[tr][c4 * 4 + 2] = v.z; qt[tr][c4 * 4 + 3] = v.w;
            }
            __syncthreads();
            float* op = out + ((size_t)b * D + c0) * HW + hw0 + th * 64;
#pragma unroll
            for (int i = 0; i < 4; ++i) {
                int e = tid + 256 * i;         // r(64 ch) x h4(16), float4 along hw
                int r = e >> 4, h4 = e & 15;
                float4 q;
                q.x = qt[h4 * 4 + 0][r]; q.y = qt[h4 * 4 + 1][r];
                q.z = qt[h4 * 4 + 2][r]; q.w = qt[h4 * 4 + 3][r];
                *(float4*)(op + (size_t)r * HW + h4 * 4) = q;
            }
        }
    }
}

extern "C" void kernel_launch(void* const* d_in, const int* in_sizes, int n_in,
                              void* d_out, int out_size, void* d_ws, size_t ws_size,
                              hipStream_t stream) {
    const float* z   = (const float*)d_in[0];   // [16,512,32,32]
    const float* emb = (const float*)d_in[1];   // [2048,512]
    char* ws = (char*)d_ws;
    __hip_bfloat16* zb   = (__hip_bfloat16*)(ws + WS_ZB);
    __hip_bfloat16* eb   = (__hip_bfloat16*)(ws + WS_EB);
    float*          esq  = (float*)(ws + WS_ESQ);
    unsigned int*   minb = (unsigned int*)(ws + WS_MINB);
    float*          xsq  = (float*)(ws + WS_XSQ);
    float*          parts= (float*)(ws + WS_PARTS);
    unsigned int*   sc   = (unsigned int*)(ws + WS_SCNT);
    unsigned int*   cnt2 = (unsigned int*)(ws + WS_CNT2);
    float* out = (float*)d_out;

    hipMemsetAsync(ws + WS_XSQ, 0, (WS_CNT2 + 4) - WS_XSQ, stream);  // xsq+parts+scnt+cnt2
    kp <<<4096, 256, 0, stream>>>(z, emb, zb, eb, esq, xsq, minb);
    kg2<<<2048, 256, 0, stream>>>(zb, eb, esq, emb, xsq, minb, sc, cnt2, parts, out);
}

// Round 7
// 165.028 us; speedup vs baseline: 1.6706x; 1.6706x over previous
//
#include <hip/hip_runtime.h>
#include <hip/hip_bf16.h>

// Problem constants
#define D       512       // embedding dim (= C)
#define K       2048      // codebook size
#define HW      1024      // 32*32
#define N_TOK   16384     // 16*HW
#define NUMEL   8388608   // 16*512*32*32

typedef __attribute__((ext_vector_type(8))) short  short8;   // 8 bf16 = 4 VGPRs
typedef __attribute__((ext_vector_type(4))) float  floatx4;

// async global->LDS DMA, 16 B per lane; LDS dest is wave-uniform base + lane*16
#define GLD_LDS16(gptr, lptr) \
    __builtin_amdgcn_global_load_lds((const __attribute__((address_space(1))) void*)(gptr), \
                                     (__attribute__((address_space(3))) void*)(lptr), 16, 0, 0)

// ---- ws layout (bytes) ----
#define WS_ZB    0           // bf16 [16384][512]
#define WS_EB    16777216    // bf16 [2048][512]
#define WS_ESQ   18874368    // f32  [2048]
#define WS_MINB  18882560    // u32  [16384] packed (21-bit dist key | 11-bit idx); init in kp
#define WS_XSQ   18948096    // f32  [16384] per-token sum z^2       (memset 0)
#define WS_PARTS 19013632    // f32  [256]   loss partials           (memset 0)
#define WS_CNT2  19014656    // u32  [1]     global completion       (memset 0)
// memset region: WS_XSQ .. WS_CNT2+4 (contiguous, 66564 B)

// monotone fp32 -> sortable u32, and its inverse
__device__ __forceinline__ unsigned int fkey(float f) {
    unsigned int b = __float_as_uint(f);
    return b ^ ((unsigned int)((int)b >> 31) | 0x80000000u);
}
__device__ __forceinline__ float unfkey(unsigned int u) {
    unsigned int b = (u & 0x80000000u) ? (u ^ 0x80000000u) : ~u;
    return __uint_as_float(b);
}

// ---------------- Kernel P: fused prep ----------------
// blocks [0,2048): z NCHW fp32 -> zb bf16 (transpose+cast) + xsq accumulate + minb init
// blocks [2048,4096): emb row -> eb bf16 + e_sq
__global__ __launch_bounds__(256) void kp(const float* __restrict__ z,
                                          const float* __restrict__ emb,
                                          __hip_bfloat16* __restrict__ zb,
                                          __hip_bfloat16* __restrict__ eb,
                                          float* __restrict__ esq,
                                          float* __restrict__ xsq,
                                          unsigned int* __restrict__ minb) {
    int blk = blockIdx.x;
    int tid = threadIdx.x;
    if (blk < 2048) {
        if (tid < 8) minb[blk * 8 + tid] = 0xFFFFFFFFu;
        __shared__ float t[64][65];
        __shared__ float ps[4][64];
        int b  = blk >> 7;
        int dt = (blk >> 4) & 7;
        int nt = blk & 15;
        int d0 = dt * 64, n0 = nt * 64;
        const float* zp = z + ((size_t)b * D + d0) * HW + n0;
#pragma unroll
        for (int i = 0; i < 4; ++i) {
            int e = tid + 256 * i;     // r(64 ch) x c4(16)
            int r = e >> 4, c4 = e & 15;
            float4 v = *(const float4*)(zp + (size_t)r * HW + c4 * 4);
            t[r][c4 * 4 + 0] = v.x; t[r][c4 * 4 + 1] = v.y;
            t[r][c4 * 4 + 2] = v.z; t[r][c4 * 4 + 3] = v.w;
        }
        __syncthreads();
        {   // xsq partial: quad q covers 16 channels of one token column
            int col = tid & 63, q = tid >> 6;
            float p = 0.f;
#pragma unroll
            for (int j = 0; j < 16; ++j) { float v = t[q * 16 + j][col]; p += v * v; }
            ps[q][col] = p;
        }
        __syncthreads();
        if (tid < 64)
            atomicAdd(&xsq[b * HW + n0 + tid], ps[0][tid] + ps[1][tid] + ps[2][tid] + ps[3][tid]);
        __hip_bfloat16* op = zb + ((size_t)(b * HW + n0)) * D + d0;
#pragma unroll
        for (int i = 0; i < 4; ++i) {
            int e = tid + 256 * i;     // rn(64 tok) x cd4(16)
            int rn = e >> 4, cd4 = e & 15;
            __hip_bfloat16 q0 = __float2bfloat16(t[cd4 * 4 + 0][rn]);
            __hip_bfloat16 q1 = __float2bfloat16(t[cd4 * 4 + 1][rn]);
            __hip_bfloat16 q2 = __float2bfloat16(t[cd4 * 4 + 2][rn]);
            __hip_bfloat16 q3 = __float2bfloat16(t[cd4 * 4 + 3][rn]);
            ushort4 u;
            u.x = *(unsigned short*)&q0; u.y = *(unsigned short*)&q1;
            u.z = *(unsigned short*)&q2; u.w = *(unsigned short*)&q3;
            *(ushort4*)(op + (size_t)rn * D + cd4 * 4) = u;
        }
    } else {
        int k = blk - 2048;
        const float* ep = emb + (size_t)k * D;
        float s = 0.f;
        for (int d = tid; d < D; d += 256) {
            float v = ep[d];
            s += v * v;
            eb[(size_t)k * D + d] = __float2bfloat16(v);
        }
#pragma unroll
        for (int o = 32; o; o >>= 1) s += __shfl_down(s, o);
        __shared__ float ls[4];
        if ((tid & 63) == 0) ls[tid >> 6] = s;
        __syncthreads();
        if (tid == 0) esq[k] = ls[0] + ls[1] + ls[2] + ls[3];
    }
}

// ---------------- Kernel G: bf16 MFMA GEMM + fused argmin (R4-proven, 63.5 us) ----------------
// grid 2048 blocks = 128 mtiles x 16 ktiles (16 consecutive blocks share the A strip,
// dispatched simultaneously across XCDs). LDS XOR col swizzle -> 0 bank conflicts.
__global__ __launch_bounds__(256) void kg(const __hip_bfloat16* __restrict__ zb,
                                          const __hip_bfloat16* __restrict__ eb,
                                          const float* __restrict__ esq,
                                          unsigned int* __restrict__ minb) {
    __shared__ __hip_bfloat16 As[128 * 64];   // flat, unpadded (global_load_lds dest)
    __shared__ __hip_bfloat16 Bs[128 * 64];

    int mtile = blockIdx.x >> 4;
    int ktile = blockIdx.x & 15;

    int tid  = threadIdx.x;
    int wv   = tid >> 6;
    int lane = tid & 63;
    int wm = wv >> 1, wn = wv & 1;   // 2x2 wave grid, each wave 64x64
    int lrow  = lane & 15;
    int lquad = lane >> 4;
    int rl = lane >> 3, c8 = lane & 7;      // staging: 8 rows x 8 uint4 per wave-call
    int csw = c8 ^ rl;                      // swizzled global col for this lane's slot
    int swz = lrow & 7;                     // read-side row swizzle

    floatx4 acc[4][4];
#pragma unroll
    for (int i = 0; i < 4; ++i)
#pragma unroll
        for (int j = 0; j < 4; ++j) acc[i][j] = (floatx4){0.f, 0.f, 0.f, 0.f};

    const uint4* Ag = (const uint4*)(zb + (size_t)mtile * 128 * D);  // [128][64] uint4
    const uint4* Bg = (const uint4*)(eb + (size_t)ktile * 128 * D);

    for (int d0 = 0; d0 < D; d0 += 64) {
        int c0 = d0 >> 3;   // uint4 col offset
#pragma unroll
        for (int ch = 0; ch < 4; ++ch) {
            int rbase = wv * 32 + ch * 8;    // wave-uniform
            GLD_LDS16(Ag + (size_t)(rbase + rl) * 64 + c0 + csw, &As[rbase * 64]);
            GLD_LDS16(Bg + (size_t)(rbase + rl) * 64 + c0 + csw, &Bs[rbase * 64]);
        }
        __syncthreads();
#pragma unroll
        for (int ks = 0; ks < 2; ++ks) {
            short8 af[4], bfr[4];
#pragma unroll
            for (int i = 0; i < 4; ++i) {
                int cL = (ks * 4 + lquad) ^ swz;          // swizzled uint4 col
                af[i]  = *(const short8*)&As[(wm * 64 + i * 16 + lrow) * 64 + (cL << 3)];
                bfr[i] = *(const short8*)&Bs[(wn * 64 + i * 16 + lrow) * 64 + (cL << 3)];
            }
#pragma unroll
            for (int i = 0; i < 4; ++i)
#pragma unroll
                for (int j = 0; j < 4; ++j)
                    acc[i][j] = __builtin_amdgcn_mfma_f32_16x16x32_bf16(af[i], bfr[j], acc[i][j], 0, 0, 0);
        }
        __syncthreads();
    }

    // epilogue: dist = esq[k] - 2*dot; argmin via u32 key = trunc-fkey | idx
    float es[4];
#pragma unroll
    for (int j = 0; j < 4; ++j) es[j] = esq[ktile * 128 + wn * 64 + j * 16 + lrow];

#pragma unroll
    for (int i = 0; i < 4; ++i) {
#pragma unroll
        for (int r = 0; r < 4; ++r) {
            int m_g = mtile * 128 + wm * 64 + i * 16 + lquad * 4 + r;  // C/D: row=quad*4+reg
            unsigned int best = 0xFFFFFFFFu;
#pragma unroll
            for (int j = 0; j < 4; ++j) {
                float dist = es[j] - 2.0f * acc[i][j][r];
                unsigned int kidx = (unsigned int)(ktile * 128 + wn * 64 + j * 16 + lrow);
                unsigned int p = (fkey(dist) & 0xFFFFF800u) | kidx;
                best = p < best ? p : best;
            }
#pragma unroll
            for (int o = 1; o < 16; o <<= 1) {
                unsigned int other = __shfl_xor(best, o);
                best = other < best ? other : best;
            }
            if (lrow == 0) atomicMin(&minb[m_g], best);
        }
    }
}

// ---------------- Kernel O3: gather + NCHW write + loss, double-buffered ----------------
// 512 blocks x 256 thr: block = 64-token strip x 256-channel half, processed as
// 4 subtiles of 64 channels with double-buffered qt (ONE barrier per subtile:
// subtile k+1's gather loads overlap subtile k's transposed global writes).
__global__ __launch_bounds__(256) void ko3(const float* __restrict__ emb,
                                           const unsigned int* __restrict__ minb,
                                           const float* __restrict__ xsq,
                                           float* __restrict__ out,
                                           float* __restrict__ parts,
                                           unsigned int* __restrict__ cnt2) {
    __shared__ int idx[64];
    __shared__ float qt[2][64][65];   // 33.3 KB, 65-stride: 2-way (free) both phases
    __shared__ float red[4];
    __shared__ int finflag;
    int blk = blockIdx.x;
    int strip = blk >> 1;             // 0..255 : token strip (b, hw0..hw0+63)
    int chalf = blk & 1;              // channel half
    int b = strip >> 4, hw0 = (strip & 15) * 64;
    int tid = threadIdx.x;
    unsigned int mykey = 0;
    if (tid < 64) {
        mykey = minb[strip * 64 + tid];
        idx[tid] = (int)(mykey & 0x7FFu);
    }
    if (tid == 0) finflag = 0;
    __syncthreads();

    // ---- loss partial (chalf==0 blocks cover each token once) ----
    if (chalf == 0 && tid < 64) {
        float v = xsq[strip * 64 + tid] + unfkey(mykey & 0xFFFFF800u);
#pragma unroll
        for (int o = 32; o; o >>= 1) v += __shfl_down(v, o);
        if (tid == 0) {
            parts[strip] = v;
            __threadfence();
            finflag = (atomicAdd(cnt2, 1u) == 255u);
        }
    }

    // ---- 4 subtiles, double-buffered ----
#pragma unroll
    for (int s = 0; s < 4; ++s) {
        int c0 = chalf * 256 + s * 64;
        int p = s & 1;
        // gather subtile s into buf p (overlaps writes of subtile s-1 from buf p^1)
#pragma unroll
        for (int i = 0; i < 4; ++i) {
            int e = tid + 256 * i;           // tr(64) x c4(16): 256 B coalesced rows
            int tr = e >> 4, c4 = e & 15;
            float4 v = *(const float4*)(emb + (size_t)idx[tr] * D + c0 + c4 * 4);
            qt[p][tr][c4 * 4 + 0] = v.x; qt[p][tr][c4 * 4 + 1] = v.y;
            qt[p][tr][c4 * 4 + 2] = v.z; qt[p][tr][c4 * 4 + 3] = v.w;
        }
        __syncthreads();                     // buf p stores visible; prev-iter reads done
        float* op = out + ((size_t)b * D + c0) * HW + hw0;
#pragma unroll
        for (int i = 0; i < 4; ++i) {
            int e = tid + 256 * i;           // r(64 ch) x h4(16), float4 along hw
            int r = e >> 4, h4 = e & 15;
            float4 q;
            q.x = qt[p][h4 * 4 + 0][r]; q.y = qt[p][h4 * 4 + 1][r];
            q.z = qt[p][h4 * 4 + 2][r]; q.w = qt[p][h4 * 4 + 3][r];
            *(float4*)(op + (size_t)r * HW + h4 * 4) = q;
        }
    }

    // ---- final loss reduce by the last-finishing chalf==0 block ----
    __syncthreads();
    if (finflag) {
        float sv = (tid < 256) ? atomicAdd(&parts[tid], 0.0f) : 0.f;  // coherent read, 256 partials
#pragma unroll
        for (int o = 32; o; o >>= 1) sv += __shfl_down(sv, o);
        if ((tid & 63) == 0) red[tid >> 6] = sv;
        __syncthreads();
        if (tid == 0)
            out[NUMEL] = 1.25f * (red[0] + red[1] + red[2] + red[3]) / 8388608.0f;
    }
}

extern "C" void kernel_launch(void* const* d_in, const int* in_sizes, int n_in,
                              void* d_out, int out_size, void* d_ws, size_t ws_size,
                              hipStream_t stream) {
    const float* z   = (const float*)d_in[0];   // [16,512,32,32]
    const float* emb = (const float*)d_in[1];   // [2048,512]
    char* ws = (char*)d_ws;
    __hip_bfloat16* zb   = (__hip_bfloat16*)(ws + WS_ZB);
    __hip_bfloat16* eb   = (__hip_bfloat16*)(ws + WS_EB);
    float*          esq  = (float*)(ws + WS_ESQ);
    unsigned int*   minb = (unsigned int*)(ws + WS_MINB);
    float*          xsq  = (float*)(ws + WS_XSQ);
    float*          parts= (float*)(ws + WS_PARTS);
    unsigned int*   cnt2 = (unsigned int*)(ws + WS_CNT2);
    float* out = (float*)d_out;

    hipMemsetAsync(ws + WS_XSQ, 0, (WS_CNT2 + 4) - WS_XSQ, stream);  // xsq+parts+cnt2
    kp <<<4096, 256, 0, stream>>>(z, emb, zb, eb, esq, xsq, minb);
    kg <<<2048, 256, 0, stream>>>(zb, eb, esq, minb);
    ko3<<< 512, 256, 0, stream>>>(emb, minb, xsq, out, parts, cnt2);
}